// Round 5
// baseline (154.317 us; speedup 1.0000x reference)
//
#include <hip/hip_runtime.h>

// BCH truncated series on 3D periodic velocity fields (fp32, B=2, D=3, 128^3).
// out_i = L_i + R_i + 0.25 * sum_j [ dL_i/dx_j * R_j - dR_i/dx_j * L_j ]
//
// R5 = R4 + amdgpu_waves_per_eu(2): the ONLY change vs R4.
// R0/R4 evidence: compiler's default max-occupancy heuristic caps the kernel
// at 44 VGPRs, splitting the 42-load batch into ~6-8 serialized
// load->waitcnt->use rounds; each wave pays full memory latency repeatedly
// (HBM 25%, VALU 10%, occupancy 44% -> latency-bound with an empty memory
// pipe). waves_per_eu(2) relaxes the register budget to ~256 VGPRs so the
// scheduler can keep the whole batch in flight: one latency round per wave,
// ~42-deep MLP. TLP drops (~2-4 waves/EU) but outstanding-bytes math says
// that's still >> enough to cover latency.

namespace {
constexpr int NX = 128, NY = 128, NZ = 128;
constexpr int XS = NY * NZ;   // x stride = 16384 floats
constexpr int CS = NX * XS;   // channel stride

__device__ inline float4 ld4(const float* p) { return *(const float4*)p; }

__device__ inline float4 f4sub(float4 a, float4 b) {
    return make_float4(a.x - b.x, a.y - b.y, a.z - b.z, a.w - b.w);
}
__device__ inline float4 f4add(float4 a, float4 b) {
    return make_float4(a.x + b.x, a.y + b.y, a.z + b.z, a.w + b.w);
}
__device__ inline float4 f4mul(float4 a, float4 b) {
    return make_float4(a.x * b.x, a.y * b.y, a.z * b.z, a.w * b.w);
}
// a*b + c
__device__ inline float4 f4fma(float4 a, float4 b, float4 c) {
    return make_float4(fmaf(a.x, b.x, c.x), fmaf(a.y, b.y, c.y),
                       fmaf(a.z, b.z, c.z), fmaf(a.w, b.w, c.w));
}
// c - a*b
__device__ inline float4 f4fms(float4 a, float4 b, float4 c) {
    return make_float4(fmaf(-a.x, b.x, c.x), fmaf(-a.y, b.y, c.y),
                       fmaf(-a.z, b.z, c.z), fmaf(-a.w, b.w, c.w));
}
} // namespace

__global__ void __launch_bounds__(256)
__attribute__((amdgpu_waves_per_eu(2)))
bch_kernel(const float* __restrict__ L, const float* __restrict__ R,
           float* __restrict__ O)
{
    const int tid = blockIdx.x * 256 + threadIdx.x;   // 20 bits
    const int zc  = tid & 31;                         // z-chunk index
    const int y   = (tid >> 5) & 127;
    const int x   = (tid >> 12) & 127;
    const int b   = tid >> 19;
    const int z0  = zc << 2;

    const int xp = (x + 1) & 127, xm = (x - 1) & 127;
    const int yp = (y + 1) & 127, ym = (y - 1) & 127;
    const int ozm = ((z0 - 1) & 127) - z0;   // rel offset to wrapped z0-1
    const int ozp = ((z0 + 4) & 127) - z0;   // rel offset to wrapped z0+4

    // ---- one dependency-free batch: 30 float4 + 12 scalar loads ----
    float4 lC[3], rC[3], lXP[3], lXM[3], rXP[3], rXM[3],
           lYP[3], lYM[3], rYP[3], rYM[3];
    float  lzm[3], lzp[3], rzm[3], rzp[3];
    int    occ[3];
#pragma unroll
    for (int c = 0; c < 3; ++c) {
        const int bc  = (b * 3 + c) * NX;
        const int oc  = (bc + x)  * XS + y  * NZ + z0;
        const int oxp = (bc + xp) * XS + y  * NZ + z0;
        const int oxm = (bc + xm) * XS + y  * NZ + z0;
        const int oyp = (bc + x)  * XS + yp * NZ + z0;
        const int oym = (bc + x)  * XS + ym * NZ + z0;
        occ[c] = oc;
        lC[c]  = ld4(L + oc);   rC[c]  = ld4(R + oc);
        lXP[c] = ld4(L + oxp);  rXP[c] = ld4(R + oxp);
        lXM[c] = ld4(L + oxm);  rXM[c] = ld4(R + oxm);
        lYP[c] = ld4(L + oyp);  rYP[c] = ld4(R + oyp);
        lYM[c] = ld4(L + oym);  rYM[c] = ld4(R + oym);
        lzm[c] = L[oc + ozm];   lzp[c] = L[oc + ozp];
        rzm[c] = R[oc + ozm];   rzp[c] = R[oc + ozp];
    }

#pragma unroll
    for (int i = 0; i < 3; ++i) {
        const float4 dxL = f4sub(lXP[i], lXM[i]);
        const float4 dxR = f4sub(rXP[i], rXM[i]);
        const float4 dyL = f4sub(lYP[i], lYM[i]);
        const float4 dyR = f4sub(rYP[i], rYM[i]);
        // z-derivative: shift-in-register from center + wrapped scalar halos
        const float4 dzL = make_float4(lC[i].y - lzm[i], lC[i].z - lC[i].x,
                                       lC[i].w - lC[i].y, lzp[i] - lC[i].z);
        const float4 dzR = make_float4(rC[i].y - rzm[i], rC[i].z - rC[i].x,
                                       rC[i].w - rC[i].y, rzp[i] - rC[i].z);

        float4 br = f4fms(dxR, lC[0], f4mul(dxL, rC[0]));
        br = f4fms(dyR, lC[1], f4fma(dyL, rC[1], br));
        br = f4fms(dzR, lC[2], f4fma(dzL, rC[2], br));

        float4 out = f4add(lC[i], rC[i]);
        const float4 q = make_float4(0.25f, 0.25f, 0.25f, 0.25f);
        out = f4fma(q, br, out);
        *(float4*)(O + occ[i]) = out;
    }
}

extern "C" void kernel_launch(void* const* d_in, const int* in_sizes, int n_in,
                              void* d_out, int out_size, void* d_ws, size_t ws_size,
                              hipStream_t stream)
{
    const float* L = (const float*)d_in[0];
    const float* R = (const float*)d_in[1];
    float*       O = (float*)d_out;

    dim3 grid(4096), block(256);   // 2*128*128*32 threads / 256
    bch_kernel<<<grid, block, 0, stream>>>(L, R, O);
}

// Round 6
// 152.380 us; speedup vs baseline: 1.0127x; 1.0127x over previous
//
#include <hip/hip_runtime.h>

// BCH truncated series on 3D periodic velocity fields (fp32, B=2, D=3, 128^3).
// out_i = L_i + R_i + 0.25 * sum_j [ dL_i/dx_j * R_j - dR_i/dx_j * L_j ]
//
// R6 = R4 + __launch_bounds__(256, 1): the ONLY change vs R4/R5.
// Diagnosis chain: R0/R4/R5 all show VGPR_Count=44 — the scheduler targets
// max occupancy and recycles ~2 load dest registers, splitting the 42-load
// batch into serialized load->waitcnt->use rounds; Little's law from the
// counters (2.1 TB/s, ~1.5kcy latency) says only ~5KB/CU is in flight, i.e.
// the memory pipe is essentially empty. waves_per_eu(2) (R5) only sets an
// occupancy *guarantee*; __launch_bounds__(256, 1) sets the scheduler's
// occupancy *target* to 1 wave/EU, giving it the register budget to keep the
// whole batch in flight with one s_waitcnt. Success criterion: VGPR_Count
// jumps to ~150-220. If it stays 44, next step is inline-asm loads.

namespace {
constexpr int NX = 128, NY = 128, NZ = 128;
constexpr int XS = NY * NZ;   // x stride = 16384 floats
constexpr int CS = NX * XS;   // channel stride

__device__ inline float4 ld4(const float* p) { return *(const float4*)p; }

__device__ inline float4 f4sub(float4 a, float4 b) {
    return make_float4(a.x - b.x, a.y - b.y, a.z - b.z, a.w - b.w);
}
__device__ inline float4 f4add(float4 a, float4 b) {
    return make_float4(a.x + b.x, a.y + b.y, a.z + b.z, a.w + b.w);
}
__device__ inline float4 f4mul(float4 a, float4 b) {
    return make_float4(a.x * b.x, a.y * b.y, a.z * b.z, a.w * b.w);
}
// a*b + c
__device__ inline float4 f4fma(float4 a, float4 b, float4 c) {
    return make_float4(fmaf(a.x, b.x, c.x), fmaf(a.y, b.y, c.y),
                       fmaf(a.z, b.z, c.z), fmaf(a.w, b.w, c.w));
}
// c - a*b
__device__ inline float4 f4fms(float4 a, float4 b, float4 c) {
    return make_float4(fmaf(-a.x, b.x, c.x), fmaf(-a.y, b.y, c.y),
                       fmaf(-a.z, b.z, c.z), fmaf(-a.w, b.w, c.w));
}
} // namespace

__global__ void __launch_bounds__(256, 1)
bch_kernel(const float* __restrict__ L, const float* __restrict__ R,
           float* __restrict__ O)
{
    const int tid = blockIdx.x * 256 + threadIdx.x;   // 20 bits
    const int zc  = tid & 31;                         // z-chunk index
    const int y   = (tid >> 5) & 127;
    const int x   = (tid >> 12) & 127;
    const int b   = tid >> 19;
    const int z0  = zc << 2;

    const int xp = (x + 1) & 127, xm = (x - 1) & 127;
    const int yp = (y + 1) & 127, ym = (y - 1) & 127;
    const int ozm = ((z0 - 1) & 127) - z0;   // rel offset to wrapped z0-1
    const int ozp = ((z0 + 4) & 127) - z0;   // rel offset to wrapped z0+4

    // ---- one dependency-free batch: 30 float4 + 12 scalar loads ----
    float4 lC[3], rC[3], lXP[3], lXM[3], rXP[3], rXM[3],
           lYP[3], lYM[3], rYP[3], rYM[3];
    float  lzm[3], lzp[3], rzm[3], rzp[3];
    int    occ[3];
#pragma unroll
    for (int c = 0; c < 3; ++c) {
        const int bc  = (b * 3 + c) * NX;
        const int oc  = (bc + x)  * XS + y  * NZ + z0;
        const int oxp = (bc + xp) * XS + y  * NZ + z0;
        const int oxm = (bc + xm) * XS + y  * NZ + z0;
        const int oyp = (bc + x)  * XS + yp * NZ + z0;
        const int oym = (bc + x)  * XS + ym * NZ + z0;
        occ[c] = oc;
        lC[c]  = ld4(L + oc);   rC[c]  = ld4(R + oc);
        lXP[c] = ld4(L + oxp);  rXP[c] = ld4(R + oxp);
        lXM[c] = ld4(L + oxm);  rXM[c] = ld4(R + oxm);
        lYP[c] = ld4(L + oyp);  rYP[c] = ld4(R + oyp);
        lYM[c] = ld4(L + oym);  rYM[c] = ld4(R + oym);
        lzm[c] = L[oc + ozm];   lzp[c] = L[oc + ozp];
        rzm[c] = R[oc + ozm];   rzp[c] = R[oc + ozp];
    }

#pragma unroll
    for (int i = 0; i < 3; ++i) {
        const float4 dxL = f4sub(lXP[i], lXM[i]);
        const float4 dxR = f4sub(rXP[i], rXM[i]);
        const float4 dyL = f4sub(lYP[i], lYM[i]);
        const float4 dyR = f4sub(rYP[i], rYM[i]);
        // z-derivative: shift-in-register from center + wrapped scalar halos
        const float4 dzL = make_float4(lC[i].y - lzm[i], lC[i].z - lC[i].x,
                                       lC[i].w - lC[i].y, lzp[i] - lC[i].z);
        const float4 dzR = make_float4(rC[i].y - rzm[i], rC[i].z - rC[i].x,
                                       rC[i].w - rC[i].y, rzp[i] - rC[i].z);

        float4 br = f4fms(dxR, lC[0], f4mul(dxL, rC[0]));
        br = f4fms(dyR, lC[1], f4fma(dyL, rC[1], br));
        br = f4fms(dzR, lC[2], f4fma(dzL, rC[2], br));

        float4 out = f4add(lC[i], rC[i]);
        const float4 q = make_float4(0.25f, 0.25f, 0.25f, 0.25f);
        out = f4fma(q, br, out);
        *(float4*)(O + occ[i]) = out;
    }
}

extern "C" void kernel_launch(void* const* d_in, const int* in_sizes, int n_in,
                              void* d_out, int out_size, void* d_ws, size_t ws_size,
                              hipStream_t stream)
{
    const float* L = (const float*)d_in[0];
    const float* R = (const float*)d_in[1];
    float*       O = (float*)d_out;

    dim3 grid(4096), block(256);   // 2*128*128*32 threads / 256
    bch_kernel<<<grid, block, 0, stream>>>(L, R, O);
}